// Round 8
// baseline (462.426 us; speedup 1.0000x reference)
//
#include <hip/hip_runtime.h>

#define NFFT    4096
#define NBINS   2049
#define TFRAMES 4096
#define HOP     1024
#define LFULL   4197376   // (TFRAMES-1)*HOP + NFFT
#define LOUT    4193280   // LFULL - NFFT  (== out_size/2 exactly)
#define CROP    2048      // NFFT/2
#define RS      2064      // transposed row stride in floats (16B-aligned rows)
#define P0TAIL  4192256   // plane-0 valid on [0,P0TAIL); NOTE: == LOUT-1024 exactly

// ---- per-phase LDS swizzles (all 4 access patterns 2-way max = free) ----
__device__ __forceinline__ int SW1(int p) {
    return p ^ (((p >> 6) & 3) | (((p >> 9) & 3) << 2) | (((p >> 8) & 1) << 4));
}
__device__ __forceinline__ int SW2(int p) {
    return p ^ (((p >> 8) & 3) << 3);
}

// radix-4 DIT butterfly, no twiddle
__device__ __forceinline__ void b4(float& x0r, float& x0i, float& x1r, float& x1i,
                                   float& x2r, float& x2i, float& x3r, float& x3i) {
    float a0r = x0r + x2r, a0i = x0i + x2i;
    float a1r = x0r - x2r, a1i = x0i - x2i;
    float a2r = x1r + x3r, a2i = x1i + x3i;
    float a3r = x1r - x3r, a3i = x1i - x3i;
    x0r = a0r + a2r;  x0i = a0i + a2i;
    x1r = a1r - a3i;  x1i = a1i + a3r;   // inverse FFT: y1 = a1 + i*a3
    x2r = a0r - a2r;  x2i = a0i - a2i;
    x3r = a1r + a3i;  x3i = a1i - a3r;
}

// radix-4 DIT butterfly with twiddle w = e^{+i*ang} = (c1,s1)
__device__ __forceinline__ void b4t(float& x0r, float& x0i, float& x1r, float& x1i,
                                    float& x2r, float& x2i, float& x3r, float& x3i,
                                    float c1, float s1) {
    float c2 = c1 * c1 - s1 * s1, s2 = 2.0f * c1 * s1;
    float c3 = c2 * c1 - s2 * s1, s3 = c2 * s1 + s2 * c1;
    float t1r = x1r * c1 - x1i * s1, t1i = x1r * s1 + x1i * c1;
    float t2r = x2r * c2 - x2i * s2, t2i = x2r * s2 + x2i * c2;
    float t3r = x3r * c3 - x3i * s3, t3i = x3r * s3 + x3i * c3;
    float a0r = x0r + t2r, a0i = x0i + t2i;
    float a1r = x0r - t2r, a1i = x0i - t2i;
    float a2r = t1r + t3r, a2i = t1i + t3i;
    float a3r = t1r - t3r, a3i = t1i - t3i;
    x0r = a0r + a2r;  x0i = a0i + a2i;
    x1r = a1r - a3i;  x1i = a1i + a3r;
    x2r = a0r - a2r;  x2i = a0i - a2i;
    x3r = a1r + a3i;  x3i = a1i - a3r;
}

#define C16_INIT { 1.0f,  0.923879532511287f,  0.707106781186548f,  0.382683432365090f, \
                   0.0f, -0.382683432365090f, -0.707106781186548f, -0.923879532511287f, \
                  -1.0f, -0.923879532511287f, -0.707106781186548f, -0.382683432365090f, \
                   0.0f,  0.382683432365090f,  0.707106781186548f,  0.923879532511287f }
#define S16_INIT { 0.0f,  0.382683432365090f,  0.707106781186548f,  0.923879532511287f, \
                   1.0f,  0.923879532511287f,  0.707106781186548f,  0.382683432365090f, \
                   0.0f, -0.382683432365090f, -0.707106781186548f, -0.923879532511287f, \
                  -1.0f, -0.923879532511287f, -0.707106781186548f, -0.382683432365090f }

// ---------------- transpose (incl. f=2048 edge row): z[ch][f][t] -> zt[ch][t][f] ----------------
__global__ __launch_bounds__(256) void transpose64(
    const float* __restrict__ z, float* __restrict__ zt)
{
    __shared__ float tile[64][65];
    const int ch = blockIdx.z;
    const int f0 = blockIdx.x * 64;     // 0..2048 (last tile: only f=2048 valid)
    const int t0 = blockIdx.y * 64;
    const int tx = threadIdx.x & 15;
    const int ty = threadIdx.x >> 4;
    const float* src = z + (size_t)ch * NBINS * TFRAMES;
    float* dst = zt + (size_t)ch * TFRAMES * RS;

    #pragma unroll
    for (int k = 0; k < 4; ++k) {
        int fl = ty + 16 * k;
        if (f0 + fl < NBINS) {
            float4 v = *(const float4*)(src + (size_t)(f0 + fl) * TFRAMES + t0 + 4 * tx);
            tile[fl][4 * tx + 0] = v.x;
            tile[fl][4 * tx + 1] = v.y;
            tile[fl][4 * tx + 2] = v.z;
            tile[fl][4 * tx + 3] = v.w;
        }
    }
    __syncthreads();
    if (f0 + 4 * tx < NBINS) {          // guard: edge tile writes only column 2048 quad
        #pragma unroll
        for (int k = 0; k < 4; ++k) {
            int tl = ty + 16 * k;
            float4 v = make_float4(tile[4 * tx + 0][tl], tile[4 * tx + 1][tl],
                                   tile[4 * tx + 2][tl], tile[4 * tx + 3][tl]);
            *(float4*)(dst + (size_t)(t0 + tl) * RS + f0 + 4 * tx) = v;
        }
    }
}

// ---------------- 4 frames/block: register IFFT + sliding-window OLA + plain stores ----------------
// Frame t=4g+k, sample n=256m+T -> cropped Q = 4096g - 2048 + 256*(4k+m) + T.
// Group tile = 32 chunks at Sc = 4096g-2048; chunk 4k+m complete after frame k ->
// flush 4 chunks/frame, keep a 16-slot sliding window (32 regs, not 56).
__global__ __launch_bounds__(256, 3) void fft4(
    const float* __restrict__ zt,      // [2][TFRAMES][RS]
    float* __restrict__ planes)        // [2 planes][2 ch][LOUT]
{
    __shared__ float LRe[NFFT];
    __shared__ float LIm[NFFT];
    const int g = blockIdx.x;          // frames 4g..4g+3
    const int T = threadIdx.x;
    const float C16[16] = C16_INIT;
    const float S16[16] = S16_INIT;

    // twiddles depend only on T -> hoisted
    const int H = T >> 4, j = T & 15;
    float cb, sb;
    __sincosf((float)j * (6.283185307179586f / 256.0f), &sb, &cb);
    float cd = cb * cb - sb * sb, sd = 2.0f * cb * sb;
    float c2s = cd * cd - sd * sd, s2s = 2.0f * cd * sd;    // j*2pi/64
    float c5, s5;
    __sincosf((float)T * (6.283185307179586f / 4096.0f), &s5, &c5);
    float cq = c5 * c5 - s5 * s5, sq = 2.0f * c5 * s5;
    float c4s = cq * cq - sq * sq, s4s = 2.0f * cq * sq;    // T*2pi/1024

    const float K = 4.4703483581542969e-8f;  // 0.5 * (1.5/NFFT) / NFFT
    const int plane = g & 1;
    float* pr = planes + (size_t)plane * 2 * LOUT;
    float* pim = pr + LOUT;
    const int Sc = (g << 12) - 2048;

    float accr[16], acci[16];
    #pragma unroll
    for (int i = 0; i < 16; ++i) { accr[i] = 0.0f; acci[i] = 0.0f; }

    #pragma unroll
    for (int k = 0; k < 4; ++k) {
        const int t = 4 * g + k;
        const float* rowr = zt + (size_t)t * RS;
        const float* rowi = zt + (size_t)TFRAMES * RS + (size_t)t * RS;
        float xr[16], xi[16];

        // Phase A: n = 256m + T (coalesced), Hermitian mirror for n > 2048
        #pragma unroll
        for (int m = 0; m < 16; ++m) {
            int r = ((m & 3) << 2) | (m >> 2);       // drev4
            int n = (m << 8) + T;
            if (n <= 2048) { xr[r] = rowr[n]; xi[r] = rowi[n]; }
            else { int f = NFFT - n; xr[r] = rowr[f]; xi[r] = -rowi[f]; }
        }
        #pragma unroll
        for (int a = 0; a < 4; ++a)
            b4(xr[4*a], xi[4*a], xr[4*a+1], xi[4*a+1], xr[4*a+2], xi[4*a+2], xr[4*a+3], xi[4*a+3]);
        b4(xr[0], xi[0], xr[4], xi[4], xr[8], xi[8], xr[12], xi[12]);
        #pragma unroll
        for (int r0 = 1; r0 < 4; ++r0)
            b4t(xr[r0], xi[r0], xr[r0+4], xi[r0+4], xr[r0+8], xi[r0+8], xr[r0+12], xi[r0+12],
                C16[r0], S16[r0]);
        {
            int G = ((T & 3) << 6) | (((T >> 2) & 3) << 4) | (((T >> 4) & 3) << 2) | ((T >> 6) & 3);
            int p0 = G << 4;
            #pragma unroll
            for (int r = 0; r < 16; ++r) {
                int a = SW1(p0 + r);
                LRe[a] = xr[r];  LIm[a] = xi[r];
            }
        }
        __syncthreads();

        // Phase B
        #pragma unroll
        for (int s = 0; s < 16; ++s) {
            int a = SW1((H << 8) + (s << 4) + j);
            xr[s] = LRe[a];  xi[s] = LIm[a];
        }
        if (j == 0) {
            #pragma unroll
            for (int a = 0; a < 4; ++a)
                b4(xr[4*a], xi[4*a], xr[4*a+1], xi[4*a+1], xr[4*a+2], xi[4*a+2], xr[4*a+3], xi[4*a+3]);
        } else {
            #pragma unroll
            for (int a = 0; a < 4; ++a)
                b4t(xr[4*a], xi[4*a], xr[4*a+1], xi[4*a+1], xr[4*a+2], xi[4*a+2], xr[4*a+3], xi[4*a+3],
                    c2s, s2s);
        }
        #pragma unroll
        for (int s0 = 0; s0 < 4; ++s0) {
            float c = cb * C16[s0] - sb * S16[s0];
            float s = sb * C16[s0] + cb * S16[s0];
            if (s0 == 0 && j == 0)
                b4(xr[0], xi[0], xr[4], xi[4], xr[8], xi[8], xr[12], xi[12]);
            else
                b4t(xr[s0], xi[s0], xr[s0+4], xi[s0+4], xr[s0+8], xi[s0+8], xr[s0+12], xi[s0+12], c, s);
        }
        __syncthreads();
        #pragma unroll
        for (int s = 0; s < 16; ++s) {
            int a = SW2((H << 8) + (s << 4) + j);
            LRe[a] = xr[s];  LIm[a] = xi[s];
        }
        __syncthreads();

        // Phase C: output n = 256m + T
        #pragma unroll
        for (int m = 0; m < 16; ++m) {
            int a = SW2((m << 8) + T);
            xr[m] = LRe[a];  xi[m] = LIm[a];
        }
        __syncthreads();   // LDS reads done; next frame may overwrite
        if (T == 0) {
            #pragma unroll
            for (int a = 0; a < 4; ++a)
                b4(xr[4*a], xi[4*a], xr[4*a+1], xi[4*a+1], xr[4*a+2], xi[4*a+2], xr[4*a+3], xi[4*a+3]);
        } else {
            #pragma unroll
            for (int a = 0; a < 4; ++a)
                b4t(xr[4*a], xi[4*a], xr[4*a+1], xi[4*a+1], xr[4*a+2], xi[4*a+2], xr[4*a+3], xi[4*a+3],
                    c4s, s4s);
        }
        #pragma unroll
        for (int m0 = 0; m0 < 4; ++m0) {
            float c = c5 * C16[m0] - s5 * S16[m0];
            float s = s5 * C16[m0] + c5 * S16[m0];
            if (m0 == 0 && T == 0)
                b4(xr[0], xi[0], xr[4], xi[4], xr[8], xi[8], xr[12], xi[12]);
            else
                b4t(xr[m0], xi[m0], xr[m0+4], xi[m0+4], xr[m0+8], xi[m0+8], xr[m0+12], xi[m0+12], c, s);
        }

        // window + OLA into sliding window: slot 4k+m <-> window idx m
        #pragma unroll
        for (int m = 0; m < 16; ++m) {
            float cn = c5 * C16[m] - s5 * S16[m];      // cos(2pi*n/4096), n = 256m+T
            float wn = (1.0f - cn) * K;
            accr[m] += xr[m] * wn;
            acci[m] += xi[m] * wn;
        }

        // flush 4 completed chunks (slots 4k..4k+3), shift window
        if (k < 3) {
            #pragma unroll
            for (int i = 0; i < 4; ++i) {
                int Q = Sc + ((4 * k + i) << 8) + T;
                if ((unsigned)Q < (unsigned)LOUT) { pr[Q] = accr[i]; pim[Q] = acci[i]; }
            }
            #pragma unroll
            for (int i = 0; i < 12; ++i) { accr[i] = accr[i + 4]; acci[i] = acci[i + 4]; }
            #pragma unroll
            for (int i = 12; i < 16; ++i) { accr[i] = 0.0f; acci[i] = 0.0f; }
        }
    }

    // final flush: slots 12..27 = window, slots 28..31 = zero-pad
    #pragma unroll
    for (int i = 0; i < 20; ++i) {
        int Q = Sc + ((12 + i) << 8) + T;
        float vr = (i < 16) ? accr[i] : 0.0f;
        float vi = (i < 16) ? acci[i] : 0.0f;
        if ((unsigned)Q < (unsigned)LOUT) { pr[Q] = vr; pim[Q] = vi; }
    }
}

// ---------------- sum planes (gap-aware) + normalize -> out (no memsets needed) ----------------
__global__ __launch_bounds__(256) void normalize_planes(
    const float* __restrict__ planes,
    const float* __restrict__ window,
    float* __restrict__ out)
{
    int idx = blockIdx.x * 256 + threadIdx.x;
    int p = idx * 4;
    if (p >= LOUT) return;
    const float* p0r = planes;
    const float* p0i = planes + LOUT;
    const float* p1r = planes + 2 * (size_t)LOUT;
    const float* p1i = planes + 3 * (size_t)LOUT;

    if (p >= 2048 && p < P0TAIL) {
        // interior: both planes valid, wsum = 3/4096 exactly
        float4 a0 = *(const float4*)(p0r + p), a1 = *(const float4*)(p1r + p);
        float4 b0 = *(const float4*)(p0i + p), b1 = *(const float4*)(p1i + p);
        const float inv = (float)NFFT / 3.0f;
        float4 a = make_float4((a0.x + a1.x) * inv, (a0.y + a1.y) * inv,
                               (a0.z + a1.z) * inv, (a0.w + a1.w) * inv);
        float4 b = make_float4((b0.x + b1.x) * inv, (b0.y + b1.y) * inv,
                               (b0.z + b1.z) * inv, (b0.w + b1.w) * inv);
        *(float4*)(out + p) = a;
        *(float4*)(out + LOUT + p) = b;
    } else {
        // head (p<2048: plane0 only) / tail (p>=P0TAIL: plane1 only); ws loop where needed
        for (int e = 0; e < 4; ++e) {
            int pe = p + e;
            float ar = (pe < P0TAIL) ? p0r[pe] : 0.0f;
            float ai = (pe < P0TAIL) ? p0i[pe] : 0.0f;
            float br = (pe >= 2048) ? p1r[pe] : 0.0f;
            float bi = (pe >= 2048) ? p1i[pe] : 0.0f;
            float vr = ar + br, vi = ai + bi;
            float inv;
            if (pe >= 1024 && pe < P0TAIL) {
                inv = (float)NFFT / 3.0f;
            } else {
                int P = pe + CROP;
                int t_hi = min(TFRAMES - 1, P >> 10);
                int t_lo = max(0, (P - (NFFT - HOP)) >> 10);
                float ws = 0.0f;
                for (int tt = t_lo; tt <= t_hi; ++tt) ws += window[P - (tt << 10)];
                inv = (ws >= 1e-6f) ? (1.0f / ws) : 1.0f;
            }
            out[pe]        = vr * inv;
            out[LOUT + pe] = vi * inv;
        }
    }
}

// ================= fallback path (ws too small for planes): atomic version =================
__global__ __launch_bounds__(256) void fft_reg(
    const float* __restrict__ zt, float* __restrict__ out)
{
    __shared__ float LRe[NFFT];
    __shared__ float LIm[NFFT];
    const int t = blockIdx.x;
    const int T = threadIdx.x;
    const float C16[16] = C16_INIT;
    const float S16[16] = S16_INIT;
    const float* rowr = zt + (size_t)t * RS;
    const float* rowi = zt + (size_t)TFRAMES * RS + (size_t)t * RS;
    float xr[16], xi[16];
    #pragma unroll
    for (int m = 0; m < 16; ++m) {
        int r = ((m & 3) << 2) | (m >> 2);
        int n = (m << 8) + T;
        if (n <= 2048) { xr[r] = rowr[n]; xi[r] = rowi[n]; }
        else { int f = NFFT - n; xr[r] = rowr[f]; xi[r] = -rowi[f]; }
    }
    #pragma unroll
    for (int a = 0; a < 4; ++a)
        b4(xr[4*a], xi[4*a], xr[4*a+1], xi[4*a+1], xr[4*a+2], xi[4*a+2], xr[4*a+3], xi[4*a+3]);
    b4(xr[0], xi[0], xr[4], xi[4], xr[8], xi[8], xr[12], xi[12]);
    #pragma unroll
    for (int r0 = 1; r0 < 4; ++r0)
        b4t(xr[r0], xi[r0], xr[r0+4], xi[r0+4], xr[r0+8], xi[r0+8], xr[r0+12], xi[r0+12],
            C16[r0], S16[r0]);
    {
        int G = ((T & 3) << 6) | (((T >> 2) & 3) << 4) | (((T >> 4) & 3) << 2) | ((T >> 6) & 3);
        int p0 = G << 4;
        #pragma unroll
        for (int r = 0; r < 16; ++r) { int a = SW1(p0 + r); LRe[a] = xr[r]; LIm[a] = xi[r]; }
    }
    __syncthreads();
    const int H = T >> 4, j = T & 15;
    #pragma unroll
    for (int s = 0; s < 16; ++s) { int a = SW1((H << 8) + (s << 4) + j); xr[s] = LRe[a]; xi[s] = LIm[a]; }
    float cb, sb;
    __sincosf((float)j * (6.283185307179586f / 256.0f), &sb, &cb);
    float cd = cb * cb - sb * sb, sd = 2.0f * cb * sb;
    float c2s = cd * cd - sd * sd, s2s = 2.0f * cd * sd;
    if (j == 0) {
        #pragma unroll
        for (int a = 0; a < 4; ++a)
            b4(xr[4*a], xi[4*a], xr[4*a+1], xi[4*a+1], xr[4*a+2], xi[4*a+2], xr[4*a+3], xi[4*a+3]);
    } else {
        #pragma unroll
        for (int a = 0; a < 4; ++a)
            b4t(xr[4*a], xi[4*a], xr[4*a+1], xi[4*a+1], xr[4*a+2], xi[4*a+2], xr[4*a+3], xi[4*a+3],
                c2s, s2s);
    }
    #pragma unroll
    for (int s0 = 0; s0 < 4; ++s0) {
        float c = cb * C16[s0] - sb * S16[s0];
        float s = sb * C16[s0] + cb * S16[s0];
        if (s0 == 0 && j == 0) b4(xr[0], xi[0], xr[4], xi[4], xr[8], xi[8], xr[12], xi[12]);
        else b4t(xr[s0], xi[s0], xr[s0+4], xi[s0+4], xr[s0+8], xi[s0+8], xr[s0+12], xi[s0+12], c, s);
    }
    __syncthreads();
    #pragma unroll
    for (int s = 0; s < 16; ++s) { int a = SW2((H << 8) + (s << 4) + j); LRe[a] = xr[s]; LIm[a] = xi[s]; }
    __syncthreads();
    #pragma unroll
    for (int m = 0; m < 16; ++m) { int a = SW2((m << 8) + T); xr[m] = LRe[a]; xi[m] = LIm[a]; }
    float c5, s5;
    __sincosf((float)T * (6.283185307179586f / 4096.0f), &s5, &c5);
    float cq = c5 * c5 - s5 * s5, sq = 2.0f * c5 * s5;
    float c4s = cq * cq - sq * sq, s4s = 2.0f * cq * sq;
    if (T == 0) {
        #pragma unroll
        for (int a = 0; a < 4; ++a)
            b4(xr[4*a], xi[4*a], xr[4*a+1], xi[4*a+1], xr[4*a+2], xi[4*a+2], xr[4*a+3], xi[4*a+3]);
    } else {
        #pragma unroll
        for (int a = 0; a < 4; ++a)
            b4t(xr[4*a], xi[4*a], xr[4*a+1], xi[4*a+1], xr[4*a+2], xi[4*a+2], xr[4*a+3], xi[4*a+3],
                c4s, s4s);
    }
    #pragma unroll
    for (int m0 = 0; m0 < 4; ++m0) {
        float c = c5 * C16[m0] - s5 * S16[m0];
        float s = s5 * C16[m0] + c5 * S16[m0];
        if (m0 == 0 && T == 0) b4(xr[0], xi[0], xr[4], xi[4], xr[8], xi[8], xr[12], xi[12]);
        else b4t(xr[m0], xi[m0], xr[m0+4], xi[m0+4], xr[m0+8], xi[m0+8], xr[m0+12], xi[m0+12], c, s);
    }
    const float K = 4.4703483581542969e-8f;
    const int base = (t << 10) - CROP;
    #pragma unroll
    for (int m = 0; m < 16; ++m) {
        float cn = c5 * C16[m] - s5 * S16[m];
        float wn = (1.0f - cn) * K;
        int P = base + (m << 8) + T;
        if (P >= 0 && P < LOUT) {
            atomicAdd(&out[P],        xr[m] * wn);
            atomicAdd(&out[LOUT + P], xi[m] * wn);
        }
    }
}

__global__ __launch_bounds__(256) void normalize_inplace(
    const float* __restrict__ window, float* __restrict__ out)
{
    int idx = blockIdx.x * 256 + threadIdx.x;
    int p = idx * 4;
    if (p >= LOUT) return;
    if (p >= 1024 && p < LOUT - 1024) {
        const float inv = (float)NFFT / 3.0f;
        float4* o0 = (float4*)(out + p);
        float4* o1 = (float4*)(out + LOUT + p);
        float4 a = *o0, b = *o1;
        a.x *= inv; a.y *= inv; a.z *= inv; a.w *= inv;
        b.x *= inv; b.y *= inv; b.z *= inv; b.w *= inv;
        *o0 = a; *o1 = b;
    } else {
        for (int e = 0; e < 4; ++e) {
            int pe = p + e;
            int P = pe + CROP;
            int t_hi = min(TFRAMES - 1, P >> 10);
            int t_lo = max(0, (P - (NFFT - HOP)) >> 10);
            float ws = 0.0f;
            for (int tt = t_lo; tt <= t_hi; ++tt) ws += window[P - (tt << 10)];
            float inv = (ws >= 1e-6f) ? (1.0f / ws) : 1.0f;
            out[pe]        *= inv;
            out[LOUT + pe] *= inv;
        }
    }
}

extern "C" void kernel_launch(void* const* d_in, const int* in_sizes, int n_in,
                              void* d_out, int out_size, void* d_ws, size_t ws_size,
                              hipStream_t stream) {
    const float* z      = (const float*)d_in[0];
    const float* window = (const float*)d_in[1];
    float* out = (float*)d_out;

    const size_t zt_floats = (size_t)2 * TFRAMES * RS;            // 16,908,288
    const size_t ws_need_B = zt_floats * sizeof(float);           // 67.6 MB (atomic path)
    const size_t ws_need_A = (zt_floats + (size_t)4 * LOUT) * sizeof(float);  // 134.7 MB

    if (ws_size >= ws_need_A) {
        float* zt     = (float*)d_ws;
        float* planes = zt + zt_floats;
        transpose64<<<dim3(33, 64, 2), 256, 0, stream>>>(z, zt);
        fft4<<<TFRAMES / 4, 256, 0, stream>>>(zt, planes);
        normalize_planes<<<(LOUT / 4 + 255) / 256, 256, 0, stream>>>(planes, window, out);
    } else if (ws_size >= ws_need_B) {
        float* zt = (float*)d_ws;
        hipMemsetAsync(out, 0, (size_t)2 * LOUT * sizeof(float), stream);
        transpose64<<<dim3(33, 64, 2), 256, 0, stream>>>(z, zt);
        fft_reg<<<TFRAMES, 256, 0, stream>>>(zt, out);
        normalize_inplace<<<(LOUT / 4 + 255) / 256, 256, 0, stream>>>(window, out);
    }
}